// Round 8
// baseline (4390.051 us; speedup 1.0000x reference)
//
#include <hip/hip_runtime.h>
#include <stdint.h>

// GraphAttention on MI355X — ALL I/O float32.
// X[8192][128], A[8192][8192] (0/1), W[4][128][64], a_self[4][64], a_neigh[4][64]
// -> out f32 [8192][256].
//
// KA: A f32 -> bitmask M32[N][256] via wave ballot (268 MB -> 8.4 MB stream).
// K0 W->WT bf16 + zero max-keys.  K1 MFMA projection + scores + atomicMax bounds.
// K2 fused mask/exp/softmax-num + P.V MFMA — BARRIER-FREE K-loop: B-frags and V
//    direct global->register double-buffered (XpT is L2/LLC-hot), mask slice in
//    LDS staged once; head-per-wave; ragged SPLIT=6 -> grid 768 = 3 blocks/CU.
// K3 combine/divide/relu.

#define NN    8192
#define FF    128
#define FD    64
#define HH    4
#define NSP   6                            // ragged splits: tiles 43,43,43,43,42,42
#define LOG2E 1.4426950408889634f
#define MSTR  44                           // Msl row stride (dwords): 2-way banks, free

typedef __attribute__((ext_vector_type(8))) short short8;
typedef __attribute__((ext_vector_type(4))) float f32x4;

extern "C" __device__ float __ocml_exp2_f32(float);

__device__ __forceinline__ float fast_exp2(float x) {
#if __has_builtin(__builtin_amdgcn_exp2f)
    return __builtin_amdgcn_exp2f(x);
#else
    return __ocml_exp2_f32(x);
#endif
}

__device__ __forceinline__ float bf16_to_f32(unsigned short u) {
    return __builtin_bit_cast(float, ((unsigned)u) << 16);
}
__device__ __forceinline__ unsigned f32_to_bf16_rne(float f) {
    unsigned u = __builtin_bit_cast(unsigned, f);
    u = (u + 0x7FFFu + ((u >> 16) & 1u)) >> 16;
    return u;
}
// Pack two f32 -> two bf16 (truncation) in ONE v_perm_b32.  lo -> bits[15:0].
__device__ __forceinline__ unsigned pack_bf16_trunc(float lo, float hi) {
    return __builtin_amdgcn_perm(__builtin_bit_cast(unsigned, hi),
                                 __builtin_bit_cast(unsigned, lo), 0x07060302u);
}
// bit j of v, sign-extended to all 32 bits (0 or 0xFFFFFFFF): v_bfe_i32
__device__ __forceinline__ unsigned bit_mask32(unsigned v, int j) {
#if __has_builtin(__builtin_amdgcn_sbfe)
    return (unsigned)__builtin_amdgcn_sbfe((int)v, j, 1);
#else
    return (unsigned)(-(int)((v >> j) & 1u));
#endif
}
// order-preserving float<->uint keys for atomicMax over signed floats
__device__ __forceinline__ unsigned enc_key(float f) {
    unsigned u = __builtin_bit_cast(unsigned, f);
    return (u & 0x80000000u) ? ~u : (u | 0x80000000u);
}
__device__ __forceinline__ float dec_key(unsigned k) {
    unsigned u = (k & 0x80000000u) ? (k ^ 0x80000000u) : ~k;
    return __builtin_bit_cast(float, u);
}

// ---------------- workspace layout (bytes), ~46 MiB ----------------
#define WS_XPT   0                                   // bf16 [H][64][N]
#define WS_U     (WS_XPT + HH * FD * NN * 2)         // f32  [H][N]  s_self
#define WS_V     (WS_U + HH * NN * 4)                // f32  [H][N]  s_neigh
#define WS_MK    (WS_V + HH * NN * 4)                // u32  [8]: maxU keys, maxV keys
#define WS_WT    (WS_MK + 256)                       // bf16 [H][64][128]
#define WS_ACCP  (WS_WT + HH * FD * FF * 2)          // bf16 [NSP][H][N][64]
#define WS_LP    (WS_ACCP + (size_t)NSP * HH * NN * FD * 2)  // f32 [NSP][H][N]
#define WS_M32   (WS_LP + (size_t)NSP * HH * NN * 4)         // u32 [N][256] bitmask

// ---------------- KA: A f32 -> bitmask via wave ballot ----------------
__global__ __launch_bounds__(256) void ka_bitmask(const float* __restrict__ Ag,
                                                  unsigned* __restrict__ M32) {
    const int lane = threadIdx.x & 63;
    const size_t wave_id = (size_t)((blockIdx.x * 256 + threadIdx.x) >> 6);
    const size_t stride = (size_t)8192 * 64;       // 2048 blocks * 4 waves * 64
    size_t base = wave_id * 64;
    #pragma unroll 4
    for (int s = 0; s < 128; ++s) {                // 8192*8192 / stride
        float a = Ag[base + lane];
        unsigned long long m = __ballot(a != 0.0f);
        if (lane == 0)
            *(unsigned long long*)(M32 + (base >> 5)) = m;
        base += stride;
    }
}

// ---------------- K0: W transpose + zero max-keys ----------------
__global__ void k0_transpose_w(const float* __restrict__ W,
                               unsigned short* __restrict__ WT,
                               unsigned* __restrict__ MK) {
    int b = blockIdx.x;            // 32 blocks
    int t = threadIdx.x;
    if (b == 0 && t < 8) MK[t] = 0u;   // key 0 == most-negative float
    int h = b >> 3, fb = b & 7;
    int d = t & 63, fo = t >> 6;
    #pragma unroll
    for (int i = 0; i < 4; ++i) {
        int f = fb * 16 + fo * 4 + i;
        WT[(h * FD + d) * FF + f] = (unsigned short)f32_to_bf16_rne(W[(h * FF + f) * FD + d]);
    }
}

// ---------------- K1: Xp = X @ W[h]; scores; XpT bf16; head max via atomics ----
__global__ __launch_bounds__(256) void k1_project(
        const float* __restrict__ X,               // [N][128] f32
        const unsigned short* __restrict__ WT,     // [H][64][128] bf16
        const float* __restrict__ a_self,          // [H][64] f32
        const float* __restrict__ a_neigh,
        unsigned short* __restrict__ XpT,          // [H][64][N] bf16
        float* __restrict__ U, float* __restrict__ V,
        unsigned* __restrict__ MK) {
    __shared__ __align__(16) char XsB[64 * 272];
    __shared__ __align__(16) char WsB[64 * 272];
    const int rb = blockIdx.x * 64;
    const int h  = blockIdx.y;
    const int t  = threadIdx.x;
    const float4* xs = (const float4*)(X + (size_t)rb * FF);
    #pragma unroll
    for (int i = 0; i < 8; ++i) {
        int c = i * 256 + t;
        float4 v = xs[c];
        uint2 pv;
        pv.x = f32_to_bf16_rne(v.x) | (f32_to_bf16_rne(v.y) << 16);
        pv.y = f32_to_bf16_rne(v.z) | (f32_to_bf16_rne(v.w) << 16);
        *(uint2*)(XsB + (c >> 5) * 272 + (c & 31) * 8) = pv;
    }
    const uint4* wsrc = (const uint4*)(WT + (size_t)h * FD * FF);
    #pragma unroll
    for (int i = 0; i < 4; ++i) {
        int c = i * 256 + t;
        *(uint4*)(WsB + (c >> 4) * 272 + (c & 15) * 16) = wsrc[c];
    }
    __syncthreads();
    const int lane = t & 63, wid = t >> 6;
    const int r15 = lane & 15, quad = lane >> 4;
    const int lrow = wid * 16 + r15;

    f32x4 acc[4];
    #pragma unroll
    for (int cg = 0; cg < 4; ++cg) acc[cg] = (f32x4){0.f, 0.f, 0.f, 0.f};
    #pragma unroll
    for (int kt = 0; kt < 4; ++kt) {
        short8 afr = *(const short8*)(XsB + lrow * 272 + kt * 64 + quad * 16);
        #pragma unroll
        for (int cg = 0; cg < 4; ++cg) {
            short8 bfr = *(const short8*)(WsB + (cg * 16 + r15) * 272 + kt * 64 + quad * 16);
            acc[cg] = __builtin_amdgcn_mfma_f32_16x16x32_bf16(afr, bfr, acc[cg], 0, 0, 0);
        }
    }
    float as[4], an[4];
    #pragma unroll
    for (int cg = 0; cg < 4; ++cg) {
        as[cg] = a_self[h * FD + cg * 16 + r15];
        an[cg] = a_neigh[h * FD + cg * 16 + r15];
    }
    float mu = -1e30f, mv = -1e30f;
    #pragma unroll
    for (int reg = 0; reg < 4; ++reg) {
        float s1 = 0.f, s2 = 0.f;
        #pragma unroll
        for (int cg = 0; cg < 4; ++cg) { s1 += acc[cg][reg] * as[cg]; s2 += acc[cg][reg] * an[cg]; }
        #pragma unroll
        for (int m = 1; m <= 8; m <<= 1) { s1 += __shfl_xor(s1, m); s2 += __shfl_xor(s2, m); }
        mu = fmaxf(mu, s1); mv = fmaxf(mv, s2);
        if (r15 == 0) {
            int n = rb + wid * 16 + quad * 4 + reg;
            U[h * NN + n] = s1;
            V[h * NN + n] = s2;
        }
    }
    mu = fmaxf(mu, __shfl_xor(mu, 16)); mu = fmaxf(mu, __shfl_xor(mu, 32));
    mv = fmaxf(mv, __shfl_xor(mv, 16)); mv = fmaxf(mv, __shfl_xor(mv, 32));
    if (lane == 0) {
        atomicMax(&MK[h], enc_key(mu));
        atomicMax(&MK[4 + h], enc_key(mv));
    }
    #pragma unroll
    for (int cg = 0; cg < 4; ++cg) {
        uint2 val;
        val.x = f32_to_bf16_rne(acc[cg][0]) | (f32_to_bf16_rne(acc[cg][1]) << 16);
        val.y = f32_to_bf16_rne(acc[cg][2]) | (f32_to_bf16_rne(acc[cg][3]) << 16);
        int d = cg * 16 + r15;
        int n0 = rb + wid * 16 + quad * 4;
        *(uint2*)((char*)XpT + ((size_t)(h * FD + d) * NN + n0) * 2) = val;
    }
}

// ---------------- K2: fused scores/softmax-numerator + P.V MFMA ----------------
// 4 waves = 64 rows; wave w owns head w; grid (128 row-blocks, 6 ragged splits)
// = 768 blocks = exactly 3/CU.  NO barriers in the K-loop: B-frags (XpT, L2-hot)
// and V loaded global->register, explicitly double-buffered; mask slice in LDS
// (staged once, stride-44 pad -> 2-way bank aliasing = free).
__global__ __launch_bounds__(256, 3) void k2_attend(
        const unsigned* __restrict__ M32,          // [N][256] bitmask of A
        const unsigned short* __restrict__ XpT,    // [H][64][N] bf16
        const float* __restrict__ U, const float* __restrict__ V,
        const unsigned* __restrict__ MK,
        unsigned short* __restrict__ accP,         // [NSP][H][N][64] bf16
        float* __restrict__ lP) {                  // f32 [NSP][H][N]
    __shared__ unsigned Msl[64 * MSTR];            // mask slice (<=43 dwords/row)
    const int t = threadIdx.x;
    const int lane = t & 63, wid = t >> 6;
    const int r15 = lane & 15, quad = lane >> 4;
    const int rb = blockIdx.x * 64;
    const int sp = blockIdx.y;
    const int h = wid;                             // head-per-wave
    const int KT  = (sp < 4) ? 43 : 42;            // tiles in this split
    const int kt0 = sp * 43 - ((sp > 4) ? (sp - 4) : 0);
    const int kb0 = kt0 * 32;                      // first column

    // stage mask slice: 4 threads per row, <=11 dwords each (one-time, ~11 KB)
    {
        const int row = t >> 2, part = t & 3;
        const unsigned* msrc = M32 + (size_t)(rb + row) * 256 + kt0;
        #pragma unroll
        for (int i = 0; i < 11; ++i) {
            int c = part * 11 + i;
            if (c < KT) Msl[row * MSTR + c] = msrc[c];
        }
    }

    const float M = dec_key(MK[h]) + dec_key(MK[4 + h]);
    const float qoff = -0.8f * M * LOG2E;          // q = 0.2*p + qoff == (0.2 s - M)*log2e
    float u1g[4];
    #pragma unroll
    for (int g = 0; g < 4; ++g)
        u1g[g] = (U[h * NN + rb + g * 16 + r15] - M) * LOG2E;

    f32x4 acc[4][4];
    #pragma unroll
    for (int g = 0; g < 4; ++g)
        #pragma unroll
        for (int cg = 0; cg < 4; ++cg) acc[g][cg] = (f32x4){0.f, 0.f, 0.f, 0.f};
    float lsum[4] = {0.f, 0.f, 0.f, 0.f};

    // B-frag source: lane reads XpT[h][cg*16+r15][kb0+kt*32+quad*8 .. +7] (16B)
    const char* bbase = (const char*)XpT +
        ((size_t)(h * FD + r15) * NN + kb0 + quad * 8) * 2;
    const size_t cgstep = (size_t)16 * NN * 2;
    const float* vbase = V + h * NN + kb0 + quad * 8;

    short8 bfr[2][4];
    float4 vv[2][2];
    #pragma unroll
    for (int cg = 0; cg < 4; ++cg)
        bfr[0][cg] = *(const short8*)(bbase + cg * cgstep);
    vv[0][0] = *(const float4*)(vbase);
    vv[0][1] = *(const float4*)(vbase + 4);

    __syncthreads();                               // Msl ready (only barrier)

    #pragma unroll 2
    for (int kt = 0; kt < KT; ++kt) {
        const int cur = kt & 1, nxt = cur ^ 1;
        if (kt + 1 < KT) {                         // register prefetch next tile
            #pragma unroll
            for (int cg = 0; cg < 4; ++cg)
                bfr[nxt][cg] = *(const short8*)(bbase + cg * cgstep + (size_t)(kt + 1) * 64);
            vv[nxt][0] = *(const float4*)(vbase + (kt + 1) * 32);
            vv[nxt][1] = *(const float4*)(vbase + (kt + 1) * 32 + 4);
        }
        #pragma unroll
        for (int g = 0; g < 4; ++g) {
            const unsigned mbits = Msl[(g * 16 + r15) * MSTR + kt] >> (quad * 8);
            float w[8];
            #pragma unroll
            for (int j = 0; j < 4; ++j) {
                float p = fmaf(vv[cur][0][j], LOG2E, u1g[g]);
                float q = fmaf(0.2f, p, qoff);
                float e = fast_exp2(fmaxf(p, q));
                w[j] = __builtin_bit_cast(float,
                         __builtin_bit_cast(unsigned, e) & bit_mask32(mbits, j));
            }
            #pragma unroll
            for (int j = 0; j < 4; ++j) {
                float p = fmaf(vv[cur][1][j], LOG2E, u1g[g]);
                float q = fmaf(0.2f, p, qoff);
                float e = fast_exp2(fmaxf(p, q));
                w[4 + j] = __builtin_bit_cast(float,
                         __builtin_bit_cast(unsigned, e) & bit_mask32(mbits, 4 + j));
            }
            lsum[g] += ((w[0] + w[1]) + (w[2] + w[3])) + ((w[4] + w[5]) + (w[6] + w[7]));
            uint4 pkv;
            pkv.x = pack_bf16_trunc(w[0], w[1]);
            pkv.y = pack_bf16_trunc(w[2], w[3]);
            pkv.z = pack_bf16_trunc(w[4], w[5]);
            pkv.w = pack_bf16_trunc(w[6], w[7]);
            short8 afrag = __builtin_bit_cast(short8, pkv);
            #pragma unroll
            for (int cg = 0; cg < 4; ++cg)
                acc[g][cg] = __builtin_amdgcn_mfma_f32_16x16x32_bf16(afrag, bfr[cur][cg], acc[g][cg], 0, 0, 0);
        }
    }
    // row denominators: combine the 4 quad-lanes sharing each row
    #pragma unroll
    for (int g = 0; g < 4; ++g) {
        lsum[g] += __shfl_xor(lsum[g], 16);
        lsum[g] += __shfl_xor(lsum[g], 32);
    }
    if (lane < 16) {
        #pragma unroll
        for (int g = 0; g < 4; ++g)
            lP[(size_t)(sp * HH + h) * NN + rb + g * 16 + lane] = lsum[g];
    }
    #pragma unroll
    for (int g = 0; g < 4; ++g)
        #pragma unroll
        for (int cg = 0; cg < 4; ++cg) {
            int d = cg * 16 + r15;
            #pragma unroll
            for (int reg = 0; reg < 4; ++reg) {
                int n = rb + g * 16 + quad * 4 + reg;
                accP[((size_t)(sp * HH + h) * NN + n) * FD + d] =
                    (unsigned short)f32_to_bf16_rne(acc[g][cg][reg]);
            }
        }
}

// ---------------- K3: combine splits, divide, relu, concat ----------------
__global__ void k3_combine(const unsigned short* __restrict__ accP,
                           const float* __restrict__ lP,
                           float* __restrict__ out) {
    int e = blockIdx.x * 256 + threadIdx.x;     // 2M elements: out[n][h*64+d]
    int n = e >> 8, c = e & 255;
    int h = c >> 6, d = c & 63;
    float num = 0.f, den = 0.f;
    #pragma unroll
    for (int s = 0; s < NSP; ++s) {
        num += bf16_to_f32(accP[((size_t)(s * HH + h) * NN + n) * FD + d]);
        den += lP[(size_t)(s * HH + h) * NN + n];
    }
    out[e] = fmaxf(num * __builtin_amdgcn_rcpf(den), 0.f);
}

extern "C" void kernel_launch(void* const* d_in, const int* in_sizes, int n_in,
                              void* d_out, int out_size, void* d_ws, size_t ws_size,
                              hipStream_t stream) {
    (void)in_sizes; (void)n_in; (void)out_size; (void)ws_size;
    const float* X       = (const float*)d_in[0];
    const float* A       = (const float*)d_in[1];
    const float* W       = (const float*)d_in[2];
    const float* a_self  = (const float*)d_in[3];
    const float* a_neigh = (const float*)d_in[4];
    char* ws = (char*)d_ws;
    unsigned short* XpT  = (unsigned short*)(ws + WS_XPT);
    float*          U    = (float*)(ws + WS_U);
    float*          V    = (float*)(ws + WS_V);
    unsigned*       MK   = (unsigned*)(ws + WS_MK);
    unsigned short* WT   = (unsigned short*)(ws + WS_WT);
    unsigned short* accP = (unsigned short*)(ws + WS_ACCP);
    float*          lP   = (float*)(ws + WS_LP);
    unsigned*       M32  = (unsigned*)(ws + WS_M32);
    float*          out  = (float*)d_out;

    ka_bitmask<<<dim3(2048), dim3(256), 0, stream>>>(A, M32);
    k0_transpose_w<<<dim3(32), dim3(256), 0, stream>>>(W, WT, MK);
    k1_project<<<dim3(NN / 64, HH), dim3(256), 0, stream>>>(X, WT, a_self, a_neigh, XpT, U, V, MK);
    k2_attend<<<dim3(NN / 64, NSP), dim3(256), 0, stream>>>(M32, XpT, U, V, MK, accP, lP);
    k3_combine<<<dim3(NN), dim3(256), 0, stream>>>(accP, lP, out);
}

// Round 9
// 531.122 us; speedup vs baseline: 8.2656x; 8.2656x over previous
//
#include <hip/hip_runtime.h>
#include <stdint.h>

// GraphAttention on MI355X — ALL I/O float32.
// X[8192][128], A[8192][8192] (0/1), W[4][128][64], a_self[4][64], a_neigh[4][64]
// -> out f32 [8192][256].
//
// KA: A f32 -> bitmask M32[N][264] (8 zero pad dwords/row) via wave ballot.
// K0 W->WT bf16 + zero max-keys.  K1 MFMA projection + scores + atomicMax bounds.
// K2 fused mask/exp/softmax-num + P.V MFMA — BARRIER-FREE K-loop, register
//    double-buffer with NAMED fields + constant trip count KT=44 (static
//    unroll, nothing dynamically indexed -> nothing demoted to scratch).
//    6 splits x 44 tiles, padded tiles have zero mask + clamped (in-bounds)
//    B/V source.  grid (128,6)=768 = exactly 3 blocks/CU.
// K3 combine/divide/relu.

#define NN    8192
#define FF    128
#define FD    64
#define HH    4
#define NSP   6
#define KT    44                           // constant tiles per split (padded)
#define MCOLS 264                          // M32 row stride in dwords (256 + 8 pad)
#define MSTR  45                           // Msl row stride (dwords): conflict-free
#define LOG2E 1.4426950408889634f

typedef __attribute__((ext_vector_type(8))) short short8;
typedef __attribute__((ext_vector_type(4))) float f32x4;

extern "C" __device__ float __ocml_exp2_f32(float);

__device__ __forceinline__ float fast_exp2(float x) {
#if __has_builtin(__builtin_amdgcn_exp2f)
    return __builtin_amdgcn_exp2f(x);
#else
    return __ocml_exp2_f32(x);
#endif
}

__device__ __forceinline__ float bf16_to_f32(unsigned short u) {
    return __builtin_bit_cast(float, ((unsigned)u) << 16);
}
__device__ __forceinline__ unsigned f32_to_bf16_rne(float f) {
    unsigned u = __builtin_bit_cast(unsigned, f);
    u = (u + 0x7FFFu + ((u >> 16) & 1u)) >> 16;
    return u;
}
// Pack two f32 -> two bf16 (truncation) in ONE v_perm_b32.  lo -> bits[15:0].
__device__ __forceinline__ unsigned pack_bf16_trunc(float lo, float hi) {
    return __builtin_amdgcn_perm(__builtin_bit_cast(unsigned, hi),
                                 __builtin_bit_cast(unsigned, lo), 0x07060302u);
}
// bit j of v, sign-extended to all 32 bits (0 or 0xFFFFFFFF): v_bfe_i32
__device__ __forceinline__ unsigned bit_mask32(unsigned v, int j) {
#if __has_builtin(__builtin_amdgcn_sbfe)
    return (unsigned)__builtin_amdgcn_sbfe((int)v, j, 1);
#else
    return (unsigned)(-(int)((v >> j) & 1u));
#endif
}
// order-preserving float<->uint keys for atomicMax over signed floats
__device__ __forceinline__ unsigned enc_key(float f) {
    unsigned u = __builtin_bit_cast(unsigned, f);
    return (u & 0x80000000u) ? ~u : (u | 0x80000000u);
}
__device__ __forceinline__ float dec_key(unsigned k) {
    unsigned u = (k & 0x80000000u) ? (k ^ 0x80000000u) : ~k;
    return __builtin_bit_cast(float, u);
}

// ---------------- workspace layout (bytes), ~47 MiB ----------------
#define WS_XPT   0                                   // bf16 [H][64][N]
#define WS_U     (WS_XPT + HH * FD * NN * 2)         // f32  [H][N]  s_self
#define WS_V     (WS_U + HH * NN * 4)                // f32  [H][N]  s_neigh
#define WS_MK    (WS_V + HH * NN * 4)                // u32  [8]: maxU keys, maxV keys
#define WS_WT    (WS_MK + 256)                       // bf16 [H][64][128]
#define WS_ACCP  (WS_WT + HH * FD * FF * 2)          // bf16 [NSP][H][N][64]
#define WS_LP    (WS_ACCP + (size_t)NSP * HH * NN * FD * 2)  // f32 [NSP][H][N]
#define WS_M32   (WS_LP + (size_t)NSP * HH * NN * 4)         // u32 [N][264] bitmask

// ---------------- KA: A f32 -> bitmask via wave ballot ----------------
__global__ __launch_bounds__(256) void ka_bitmask(const float* __restrict__ Ag,
                                                  unsigned* __restrict__ M32) {
    const int lane = threadIdx.x & 63;
    const size_t wave_id = (size_t)((blockIdx.x * 256 + threadIdx.x) >> 6);
    const size_t stride = (size_t)8192 * 64;       // 2048 blocks * 4 waves * 64
    size_t base = wave_id * 64;
    #pragma unroll 4
    for (int s = 0; s < 128; ++s) {                // 8192*8192 / stride
        float a = Ag[base + lane];
        unsigned long long m = __ballot(a != 0.0f);
        if (lane == 0) {
            size_t row = base >> 13;               // / 8192
            int dw = (int)((base >> 5) & 255);
            *(unsigned long long*)(M32 + row * MCOLS + dw) = m;
        }
        base += stride;
    }
    // zero the 8 pad dwords for 4 rows per block
    if (threadIdx.x < 32) {
        int row = blockIdx.x * 4 + (threadIdx.x >> 3);
        M32[(size_t)row * MCOLS + 256 + (threadIdx.x & 7)] = 0u;
    }
}

// ---------------- K0: W transpose + zero max-keys ----------------
__global__ void k0_transpose_w(const float* __restrict__ W,
                               unsigned short* __restrict__ WT,
                               unsigned* __restrict__ MK) {
    int b = blockIdx.x;            // 32 blocks
    int t = threadIdx.x;
    if (b == 0 && t < 8) MK[t] = 0u;   // key 0 == most-negative float
    int h = b >> 3, fb = b & 7;
    int d = t & 63, fo = t >> 6;
    #pragma unroll
    for (int i = 0; i < 4; ++i) {
        int f = fb * 16 + fo * 4 + i;
        WT[(h * FD + d) * FF + f] = (unsigned short)f32_to_bf16_rne(W[(h * FF + f) * FD + d]);
    }
}

// ---------------- K1: Xp = X @ W[h]; scores; XpT bf16; head max via atomics ----
__global__ __launch_bounds__(256) void k1_project(
        const float* __restrict__ X,               // [N][128] f32
        const unsigned short* __restrict__ WT,     // [H][64][128] bf16
        const float* __restrict__ a_self,          // [H][64] f32
        const float* __restrict__ a_neigh,
        unsigned short* __restrict__ XpT,          // [H][64][N] bf16
        float* __restrict__ U, float* __restrict__ V,
        unsigned* __restrict__ MK) {
    __shared__ __align__(16) char XsB[64 * 272];
    __shared__ __align__(16) char WsB[64 * 272];
    const int rb = blockIdx.x * 64;
    const int h  = blockIdx.y;
    const int t  = threadIdx.x;
    const float4* xs = (const float4*)(X + (size_t)rb * FF);
    #pragma unroll
    for (int i = 0; i < 8; ++i) {
        int c = i * 256 + t;
        float4 v = xs[c];
        uint2 pv;
        pv.x = f32_to_bf16_rne(v.x) | (f32_to_bf16_rne(v.y) << 16);
        pv.y = f32_to_bf16_rne(v.z) | (f32_to_bf16_rne(v.w) << 16);
        *(uint2*)(XsB + (c >> 5) * 272 + (c & 31) * 8) = pv;
    }
    const uint4* wsrc = (const uint4*)(WT + (size_t)h * FD * FF);
    #pragma unroll
    for (int i = 0; i < 4; ++i) {
        int c = i * 256 + t;
        *(uint4*)(WsB + (c >> 4) * 272 + (c & 15) * 16) = wsrc[c];
    }
    __syncthreads();
    const int lane = t & 63, wid = t >> 6;
    const int r15 = lane & 15, quad = lane >> 4;
    const int lrow = wid * 16 + r15;

    f32x4 acc[4];
    #pragma unroll
    for (int cg = 0; cg < 4; ++cg) acc[cg] = (f32x4){0.f, 0.f, 0.f, 0.f};
    #pragma unroll
    for (int kt = 0; kt < 4; ++kt) {
        short8 afr = *(const short8*)(XsB + lrow * 272 + kt * 64 + quad * 16);
        #pragma unroll
        for (int cg = 0; cg < 4; ++cg) {
            short8 bfr = *(const short8*)(WsB + (cg * 16 + r15) * 272 + kt * 64 + quad * 16);
            acc[cg] = __builtin_amdgcn_mfma_f32_16x16x32_bf16(afr, bfr, acc[cg], 0, 0, 0);
        }
    }
    float as[4], an[4];
    #pragma unroll
    for (int cg = 0; cg < 4; ++cg) {
        as[cg] = a_self[h * FD + cg * 16 + r15];
        an[cg] = a_neigh[h * FD + cg * 16 + r15];
    }
    float mu = -1e30f, mv = -1e30f;
    #pragma unroll
    for (int reg = 0; reg < 4; ++reg) {
        float s1 = 0.f, s2 = 0.f;
        #pragma unroll
        for (int cg = 0; cg < 4; ++cg) { s1 += acc[cg][reg] * as[cg]; s2 += acc[cg][reg] * an[cg]; }
        #pragma unroll
        for (int m = 1; m <= 8; m <<= 1) { s1 += __shfl_xor(s1, m); s2 += __shfl_xor(s2, m); }
        mu = fmaxf(mu, s1); mv = fmaxf(mv, s2);
        if (r15 == 0) {
            int n = rb + wid * 16 + quad * 4 + reg;
            U[h * NN + n] = s1;
            V[h * NN + n] = s2;
        }
    }
    mu = fmaxf(mu, __shfl_xor(mu, 16)); mu = fmaxf(mu, __shfl_xor(mu, 32));
    mv = fmaxf(mv, __shfl_xor(mv, 16)); mv = fmaxf(mv, __shfl_xor(mv, 32));
    if (lane == 0) {
        atomicMax(&MK[h], enc_key(mu));
        atomicMax(&MK[4 + h], enc_key(mv));
    }
    #pragma unroll
    for (int cg = 0; cg < 4; ++cg) {
        uint2 val;
        val.x = f32_to_bf16_rne(acc[cg][0]) | (f32_to_bf16_rne(acc[cg][1]) << 16);
        val.y = f32_to_bf16_rne(acc[cg][2]) | (f32_to_bf16_rne(acc[cg][3]) << 16);
        int d = cg * 16 + r15;
        int n0 = rb + wid * 16 + quad * 4;
        *(uint2*)((char*)XpT + ((size_t)(h * FD + d) * NN + n0) * 2) = val;
    }
}

// ---------------- K2: fused scores/softmax-numerator + P.V MFMA ----------------
// 4 waves = 64 rows; wave w owns head w; grid (128 row-blocks, 6 splits of 44
// padded tiles) = 768 = exactly 3 blocks/CU.  Barrier-free K-loop; B-frags (XpT,
// L2-hot) + V double-buffered in NAMED registers, manually 2x-unrolled.
// Mask slice in LDS (staged once; stride-45 -> 16 distinct banks, quad
// broadcast, conflict-free).  Padded tiles: mask==0, source column clamped.
struct KBuf {
    short8 f0, f1, f2, f3;     // B-frags cg=0..3
    float4 v0, v1;             // V slice (8 floats)
};

__global__ __launch_bounds__(256, 3) void k2_attend(
        const unsigned* __restrict__ M32,          // [N][264] bitmask of A
        const unsigned short* __restrict__ XpT,    // [H][64][N] bf16
        const float* __restrict__ U, const float* __restrict__ V,
        const unsigned* __restrict__ MK,
        unsigned short* __restrict__ accP,         // [NSP][H][N][64] bf16
        float* __restrict__ lP) {                  // f32 [NSP][H][N]
    __shared__ unsigned Msl[64 * MSTR];            // mask slice (44 dwords/row)
    const int t = threadIdx.x;
    const int lane = t & 63, wid = t >> 6;
    const int r15 = lane & 15, quad = lane >> 4;
    const int rb = blockIdx.x * 64;
    const int sp = blockIdx.y;
    const int h = wid;                             // head-per-wave
    const int kt0 = sp * KT;                       // first tile dword
    const int kb0 = kt0 * 32;                      // first column

    // stage mask slice: 4 threads per row, exactly 11 dwords each
    {
        const int row = t >> 2, part = t & 3;
        const unsigned* msrc = M32 + (size_t)(rb + row) * MCOLS + kt0;
        #pragma unroll
        for (int i = 0; i < 11; ++i) {
            int c = part * 11 + i;
            Msl[row * MSTR + c] = msrc[c];
        }
    }

    const float M = dec_key(MK[h]) + dec_key(MK[4 + h]);
    const float qoff = -0.8f * M * LOG2E;          // q = 0.2*p + qoff == (0.2 s - M)*log2e
    float u1g[4];
    #pragma unroll
    for (int g = 0; g < 4; ++g)
        u1g[g] = (U[h * NN + rb + g * 16 + r15] - M) * LOG2E;

    f32x4 acc[4][4];
    #pragma unroll
    for (int g = 0; g < 4; ++g)
        #pragma unroll
        for (int cg = 0; cg < 4; ++cg) acc[g][cg] = (f32x4){0.f, 0.f, 0.f, 0.f};
    float lsum[4] = {0.f, 0.f, 0.f, 0.f};

    // B-frag source: lane reads XpT[h][cg*16+r15][kb + quad*8 .. +7] (16B)
    const char* bbase = (const char*)XpT + ((size_t)(h * FD + r15) * NN + quad * 8) * 2;
    const size_t cgstep = (size_t)16 * NN * 2;
    const float* vbase = V + h * NN + quad * 8;

    KBuf A, B;
    // clamped column for tile x (padded tiles read valid finite data, mask==0)
    #define KBOF(x) ((kb0 + (x) * 32 > NN - 32) ? (NN - 32) : (kb0 + (x) * 32))
    #define PREFETCH(BUF, x) do {                                              \
        const int kb_ = KBOF(x);                                              \
        const char* p_ = bbase + (size_t)kb_ * 2;                             \
        BUF.f0 = *(const short8*)(p_);                                        \
        BUF.f1 = *(const short8*)(p_ + cgstep);                               \
        BUF.f2 = *(const short8*)(p_ + 2 * cgstep);                           \
        BUF.f3 = *(const short8*)(p_ + 3 * cgstep);                           \
        BUF.v0 = *(const float4*)(vbase + kb_);                               \
        BUF.v1 = *(const float4*)(vbase + kb_ + 4);                           \
    } while (0)

    #define PROCESS(BUF, ktv) do {                                            \
        _Pragma("unroll")                                                     \
        for (int g = 0; g < 4; ++g) {                                         \
            const unsigned mbits = Msl[(g * 16 + r15) * MSTR + (ktv)] >> (quad * 8); \
            float w[8];                                                       \
            _Pragma("unroll")                                                 \
            for (int j = 0; j < 4; ++j) {                                     \
                float p = fmaf(((const float*)&BUF.v0)[j], LOG2E, u1g[g]);    \
                float q = fmaf(0.2f, p, qoff);                                \
                float e = fast_exp2(fmaxf(p, q));                             \
                w[j] = __builtin_bit_cast(float,                              \
                         __builtin_bit_cast(unsigned, e) & bit_mask32(mbits, j)); \
            }                                                                 \
            _Pragma("unroll")                                                 \
            for (int j = 0; j < 4; ++j) {                                     \
                float p = fmaf(((const float*)&BUF.v1)[j], LOG2E, u1g[g]);    \
                float q = fmaf(0.2f, p, qoff);                                \
                float e = fast_exp2(fmaxf(p, q));                             \
                w[4 + j] = __builtin_bit_cast(float,                          \
                         __builtin_bit_cast(unsigned, e) & bit_mask32(mbits, 4 + j)); \
            }                                                                 \
            lsum[g] += ((w[0] + w[1]) + (w[2] + w[3])) + ((w[4] + w[5]) + (w[6] + w[7])); \
            uint4 pkv;                                                        \
            pkv.x = pack_bf16_trunc(w[0], w[1]);                              \
            pkv.y = pack_bf16_trunc(w[2], w[3]);                              \
            pkv.z = pack_bf16_trunc(w[4], w[5]);                              \
            pkv.w = pack_bf16_trunc(w[6], w[7]);                              \
            short8 afrag = __builtin_bit_cast(short8, pkv);                   \
            acc[g][0] = __builtin_amdgcn_mfma_f32_16x16x32_bf16(afrag, BUF.f0, acc[g][0], 0, 0, 0); \
            acc[g][1] = __builtin_amdgcn_mfma_f32_16x16x32_bf16(afrag, BUF.f1, acc[g][1], 0, 0, 0); \
            acc[g][2] = __builtin_amdgcn_mfma_f32_16x16x32_bf16(afrag, BUF.f2, acc[g][2], 0, 0, 0); \
            acc[g][3] = __builtin_amdgcn_mfma_f32_16x16x32_bf16(afrag, BUF.f3, acc[g][3], 0, 0, 0); \
        }                                                                     \
    } while (0)

    PREFETCH(A, 0);
    __syncthreads();                               // Msl ready (only barrier)

    for (int kt = 0; kt < KT; kt += 2) {
        PREFETCH(B, kt + 1);
        PROCESS(A, kt);
        PREFETCH(A, kt + 2);                       // kt+2==KT reads clamped col; unused
        PROCESS(B, kt + 1);
    }
    #undef KBOF
    #undef PREFETCH
    #undef PROCESS

    // row denominators: combine the 4 quad-lanes sharing each row
    #pragma unroll
    for (int g = 0; g < 4; ++g) {
        lsum[g] += __shfl_xor(lsum[g], 16);
        lsum[g] += __shfl_xor(lsum[g], 32);
    }
    if (lane < 16) {
        #pragma unroll
        for (int g = 0; g < 4; ++g)
            lP[(size_t)(sp * HH + h) * NN + rb + g * 16 + lane] = lsum[g];
    }
    #pragma unroll
    for (int g = 0; g < 4; ++g)
        #pragma unroll
        for (int cg = 0; cg < 4; ++cg) {
            int d = cg * 16 + r15;
            #pragma unroll
            for (int reg = 0; reg < 4; ++reg) {
                int n = rb + g * 16 + quad * 4 + reg;
                accP[((size_t)(sp * HH + h) * NN + n) * FD + d] =
                    (unsigned short)f32_to_bf16_rne(acc[g][cg][reg]);
            }
        }
}

// ---------------- K3: combine splits, divide, relu, concat ----------------
__global__ void k3_combine(const unsigned short* __restrict__ accP,
                           const float* __restrict__ lP,
                           float* __restrict__ out) {
    int e = blockIdx.x * 256 + threadIdx.x;     // 2M elements: out[n][h*64+d]
    int n = e >> 8, c = e & 255;
    int h = c >> 6, d = c & 63;
    float num = 0.f, den = 0.f;
    #pragma unroll
    for (int s = 0; s < NSP; ++s) {
        num += bf16_to_f32(accP[((size_t)(s * HH + h) * NN + n) * FD + d]);
        den += lP[(size_t)(s * HH + h) * NN + n];
    }
    out[e] = fmaxf(num * __builtin_amdgcn_rcpf(den), 0.f);
}

extern "C" void kernel_launch(void* const* d_in, const int* in_sizes, int n_in,
                              void* d_out, int out_size, void* d_ws, size_t ws_size,
                              hipStream_t stream) {
    (void)in_sizes; (void)n_in; (void)out_size; (void)ws_size;
    const float* X       = (const float*)d_in[0];
    const float* A       = (const float*)d_in[1];
    const float* W       = (const float*)d_in[2];
    const float* a_self  = (const float*)d_in[3];
    const float* a_neigh = (const float*)d_in[4];
    char* ws = (char*)d_ws;
    unsigned short* XpT  = (unsigned short*)(ws + WS_XPT);
    float*          U    = (float*)(ws + WS_U);
    float*          V    = (float*)(ws + WS_V);
    unsigned*       MK   = (unsigned*)(ws + WS_MK);
    unsigned short* WT   = (unsigned short*)(ws + WS_WT);
    unsigned short* accP = (unsigned short*)(ws + WS_ACCP);
    float*          lP   = (float*)(ws + WS_LP);
    unsigned*       M32  = (unsigned*)(ws + WS_M32);
    float*          out  = (float*)d_out;

    ka_bitmask<<<dim3(2048), dim3(256), 0, stream>>>(A, M32);
    k0_transpose_w<<<dim3(32), dim3(256), 0, stream>>>(W, WT, MK);
    k1_project<<<dim3(NN / 64, HH), dim3(256), 0, stream>>>(X, WT, a_self, a_neigh, XpT, U, V, MK);
    k2_attend<<<dim3(NN / 64, NSP), dim3(256), 0, stream>>>(M32, XpT, U, V, MK, accP, lP);
    k3_combine<<<dim3(NN), dim3(256), 0, stream>>>(accP, lP, out);
}